// Round 11
// baseline (884.317 us; speedup 1.0000x reference)
//
#include <hip/hip_runtime.h>

// InitReduceConv: out[dst[e], :] += x[src[e], :]  (E=2M edges, D=64 fp32)
//
// Round-11: occupancy-engineered 2-level radix partition + LDS-atomic gather.
//   K1 hist_super: dst -> 25 super bins (4096 rows)
//   K2 scan_super: serial scan (25 elems)
//   K3 pass1:      chunk=2048, LDS sort by super, coalesced ~656B-run flush;
//                  also accumulates global fine histogram (1563 bins)
//   K4 scan_fine:  1 block, 256-thread scan over 1563
//   K5 pass2:      chunk=2048 over super-grouped pairs -> fine bins,
//                  ~256B runs, output packed (dst&63)<<25|src (4 B)
//   K6 gather_bin: 1 block/fine bin, LDS float-atomic acc (64x65 padded),
//                  single coalesced out write. grid 1563, ~16.6 KB LDS.
//
// ws: [0,128) histS | [4K) super_start | [8K) super_cursor | [16K,24K) histF
//     [32K) fine_start | [48K) fine_cursor | [1M) binned1 int2[E] | +16M binned2 uint[E]

#define FINE_SHIFT 6
#define FINE_ROWS  64
#define MAX_FINE   2048            // NOUT rows <= 131072
#define MAX_SUPER  32
#define CHUNK1     2048
#define CHUNK2     2048

#define HS_OFF 0
#define SS_OFF 4096
#define SC_OFF 8192
#define HF_OFF 16384
#define FS_OFF 32768
#define FC_OFF 49152
#define B1_OFF (1u << 20)

// ---------- K1: super histogram ----------
__global__ void hist_super_kernel(const int* __restrict__ dst, int* __restrict__ histS,
                                  int E, int nsuper) {
    __shared__ int lh[MAX_SUPER];
    if (threadIdx.x < MAX_SUPER) lh[threadIdx.x] = 0;
    __syncthreads();
    int stride = gridDim.x * blockDim.x;
    for (int e = blockIdx.x * blockDim.x + threadIdx.x; e < E; e += stride)
        atomicAdd(&lh[dst[e] >> (FINE_SHIFT + 6)], 1);
    __syncthreads();
    if (threadIdx.x < nsuper && lh[threadIdx.x])
        atomicAdd(&histS[threadIdx.x], lh[threadIdx.x]);
}

// ---------- K2: serial scan over <=32 supers ----------
__global__ void scan_super_kernel(const int* __restrict__ histS,
                                  int* __restrict__ super_start,
                                  int* __restrict__ super_cursor, int nsuper) {
    if (threadIdx.x == 0) {
        int acc = 0;
        for (int i = 0; i < nsuper; ++i) {
            super_start[i] = acc; super_cursor[i] = acc; acc += histS[i];
        }
        super_start[nsuper] = acc;
    }
}

// ---------- K3: partition by super bin (+ fine hist) ----------
__launch_bounds__(256)
__global__ void pass1_kernel(const int* __restrict__ bidx,
                             int* __restrict__ super_cursor,
                             int2* __restrict__ binned1,
                             int* __restrict__ histF,
                             int E, int nsuper, int nfine) {
    __shared__ int2 stage[CHUNK1];       // 16 KB
    __shared__ int cntS[MAX_SUPER];
    __shared__ int adjS[MAX_SUPER];
    __shared__ int lstartS[MAX_SUPER];
    __shared__ int lh[MAX_FINE];         // 8 KB fine hist
    int t = threadIdx.x;
    int base = blockIdx.x * CHUNK1;
    int n = E - base; if (n > CHUNK1) n = CHUNK1;
    if (n <= 0) return;

    if (t < MAX_SUPER) cntS[t] = 0;
    for (int i = t; i < nfine; i += 256) lh[i] = 0;
    __syncthreads();

    for (int i = t; i < n; i += 256) {
        int d = bidx[E + base + i];
        atomicAdd(&cntS[d >> (FINE_SHIFT + 6)], 1);
        atomicAdd(&lh[d >> FINE_SHIFT], 1);
    }
    __syncthreads();

    if (t == 0) {
        int acc = 0;
        for (int i = 0; i < nsuper; ++i) { lstartS[i] = acc; acc += cntS[i]; }
    }
    __syncthreads();

    if (t < nsuper) {
        int cc = cntS[t];
        int gb = cc ? atomicAdd(&super_cursor[t], cc) : 0;
        adjS[t] = gb - lstartS[t];
        cntS[t] = lstartS[t];            // becomes scatter cursor
    }
    __syncthreads();

    for (int i = t; i < n; i += 256) {
        int s = bidx[base + i];
        int d = bidx[E + base + i];
        int pos = atomicAdd(&cntS[d >> (FINE_SHIFT + 6)], 1);
        stage[pos] = make_int2(s, d);
    }
    __syncthreads();

    for (int i = t; i < n; i += 256) {
        int2 p = stage[i];
        binned1[adjS[p.y >> (FINE_SHIFT + 6)] + i] = p;
    }
    for (int i = t; i < nfine; i += 256)
        if (lh[i]) atomicAdd(&histF[i], lh[i]);
}

// ---------- K4: scan over fine bins (1 block, 256 threads) ----------
__global__ void scan_fine_kernel(const int* __restrict__ histF,
                                 int* __restrict__ fine_start,
                                 int* __restrict__ fine_cursor, int nfine) {
    __shared__ int part[256];
    int t = threadIdx.x;
    int b0 = t * 8;
    int v[8]; int sum = 0;
#pragma unroll
    for (int k = 0; k < 8; ++k) {
        int b = b0 + k;
        v[k] = (b < nfine) ? histF[b] : 0;
        sum += v[k];
    }
    part[t] = sum;
    __syncthreads();
    for (int off = 1; off < 256; off <<= 1) {
        int x = (t >= off) ? part[t - off] : 0;
        __syncthreads();
        part[t] += x;
        __syncthreads();
    }
    int ex = (t == 0) ? 0 : part[t - 1];
#pragma unroll
    for (int k = 0; k < 8; ++k) {
        int b = b0 + k;
        if (b < nfine) { fine_start[b] = ex; fine_cursor[b] = ex; }
        ex += v[k];
    }
    if (t == 255) fine_start[nfine] = ex;   // == E
}

// ---------- K5: partition by fine bin, pack payload ----------
__launch_bounds__(256)
__global__ void pass2_kernel(const int2* __restrict__ binned1,
                             int* __restrict__ fine_cursor,
                             unsigned int* __restrict__ binned2,
                             int E, int nfine) {
    __shared__ int2 stage[CHUNK2];       // 16 KB
    __shared__ int cntF[MAX_FINE];       // 8 KB: hist -> lstart-cursor
    __shared__ int adjF[MAX_FINE];       // 8 KB: lstart -> gbase-lstart
    __shared__ int part[256];
    int t = threadIdx.x;
    int base = blockIdx.x * CHUNK2;
    int n = E - base; if (n > CHUNK2) n = CHUNK2;
    if (n <= 0) return;

    for (int i = t; i < nfine; i += 256) cntF[i] = 0;
    __syncthreads();
    for (int i = t; i < n; i += 256)
        atomicAdd(&cntF[binned1[base + i].y >> FINE_SHIFT], 1);
    __syncthreads();

    // exclusive scan over nfine (8 bins/thread + Hillis-Steele 256)
    int b0 = t * 8;
    int v[8]; int sum = 0;
#pragma unroll
    for (int k = 0; k < 8; ++k) {
        int b = b0 + k;
        v[k] = (b < nfine) ? cntF[b] : 0;
        sum += v[k];
    }
    part[t] = sum;
    __syncthreads();
    for (int off = 1; off < 256; off <<= 1) {
        int x = (t >= off) ? part[t - off] : 0;
        __syncthreads();
        part[t] += x;
        __syncthreads();
    }
    int ex = (t == 0) ? 0 : part[t - 1];
#pragma unroll
    for (int k = 0; k < 8; ++k) {
        int b = b0 + k;
        if (b < nfine) adjF[b] = ex;     // lstart
        ex += v[k];
    }
    __syncthreads();

    for (int i = t; i < nfine; i += 256) {
        int ls = adjF[i];
        int cc = cntF[i];
        int gb = cc ? atomicAdd(&fine_cursor[i], cc) : 0;
        adjF[i] = gb - ls;
        cntF[i] = ls;                    // scatter cursor
    }
    __syncthreads();

    for (int i = t; i < n; i += 256) {
        int2 p = binned1[base + i];      // L2-hot second read
        int pos = atomicAdd(&cntF[p.y >> FINE_SHIFT], 1);
        stage[pos] = p;
    }
    __syncthreads();

    for (int i = t; i < n; i += 256) {
        int2 p = stage[i];
        int f = p.y >> FINE_SHIFT;
        binned2[adjF[f] + i] =
            ((unsigned)(p.y & (FINE_ROWS - 1)) << 25) | (unsigned)p.x;
    }
}

// ---------- K6: per-bin LDS-atomic gather ----------
__launch_bounds__(256)
__global__ void gather_bin_kernel(const float4* __restrict__ x4,
                                  const int* __restrict__ fine_start,
                                  const unsigned int* __restrict__ binned2,
                                  float4* __restrict__ out4, int NOUT) {
    __shared__ float acc[FINE_ROWS * 65];   // padded stride 65 -> banks spread by row
    int t = threadIdx.x;
    int bin = blockIdx.x;
    int j0 = fine_start[bin], j1 = fine_start[bin + 1];

    for (int i = t; i < FINE_ROWS * 65; i += 256) acc[i] = 0.f;
    __syncthreads();

    int g = t >> 4, c = t & 15;             // 16 groups x 16 lanes
#pragma unroll 4
    for (int j = j0 + g; j < j1; j += 16) {
        unsigned v = binned2[j];
        int src = (int)(v & 0x1FFFFFFu);
        int ld  = (int)(v >> 25);
        float4 val = x4[(size_t)src * 16 + c];
        float* a = &acc[ld * 65 + (c << 2)];
        atomicAdd(a + 0, val.x);
        atomicAdd(a + 1, val.y);
        atomicAdd(a + 2, val.z);
        atomicAdd(a + 3, val.w);
    }
    __syncthreads();

    int rowbase = bin << FINE_SHIFT;
    for (int i = t; i < FINE_ROWS * 16; i += 256) {
        int r = i >> 4, cc = i & 15;
        int row = rowbase + r;
        if (row < NOUT) {
            float4 o;
            o.x = acc[r * 65 + cc * 4 + 0];
            o.y = acc[r * 65 + cc * 4 + 1];
            o.z = acc[r * 65 + cc * 4 + 2];
            o.w = acc[r * 65 + cc * 4 + 3];
            out4[(size_t)row * 16 + cc] = o;
        }
    }
}

// ---------- fallback: direct atomics ----------
__global__ void scatter_add_f4_kernel(const float4* __restrict__ x4,
                                      const int* __restrict__ bidx,
                                      float* __restrict__ out, int E) {
    int idx = blockIdx.x * blockDim.x + threadIdx.x;
    int total = E * 16;
    if (idx >= total) return;
    int e = idx >> 4;
    int c = idx & 15;
    int src = bidx[e];
    int dst = bidx[E + e];
    float4 v = x4[(size_t)src * 16 + c];
    float* o = out + (size_t)dst * 64 + (c << 2);
    atomicAdd(o + 0, v.x);
    atomicAdd(o + 1, v.y);
    atomicAdd(o + 2, v.z);
    atomicAdd(o + 3, v.w);
}

extern "C" void kernel_launch(void* const* d_in, const int* in_sizes, int n_in,
                              void* d_out, int out_size, void* d_ws, size_t ws_size,
                              hipStream_t stream) {
    const float* x = (const float*)d_in[0];
    const int* bidx = (const int*)d_in[1];
    float* out = (float*)d_out;

    const int E = in_sizes[1] / 2;            // 2,000,000
    const int NOUT = out_size / 64;           // 100,000 rows
    const int NSRC = in_sizes[0] / 64;        // 100,000 rows
    const int nfine = (NOUT + FINE_ROWS - 1) >> FINE_SHIFT;     // 1563
    const int nsuper = (nfine + 63) >> 6;                       // 25

    const size_t B2_OFF = (size_t)B1_OFF + (size_t)E * sizeof(int2);
    const size_t needed = B2_OFF + (size_t)E * sizeof(unsigned int);

    if ((out_size % 64) != 0 || nfine > MAX_FINE || nsuper > MAX_SUPER ||
        NSRC > (1 << 25) || ws_size < needed) {
        hipMemsetAsync(d_out, 0, (size_t)out_size * sizeof(float), stream);
        int total = E * 16;
        scatter_add_f4_kernel<<<(total + 255) / 256, 256, 0, stream>>>(
            (const float4*)x, bidx, out, E);
        return;
    }

    char* ws = (char*)d_ws;
    int* histS        = (int*)(ws + HS_OFF);
    int* super_start  = (int*)(ws + SS_OFF);
    int* super_cursor = (int*)(ws + SC_OFF);
    int* histF        = (int*)(ws + HF_OFF);
    int* fine_start   = (int*)(ws + FS_OFF);
    int* fine_cursor  = (int*)(ws + FC_OFF);
    int2* binned1     = (int2*)(ws + B1_OFF);
    unsigned int* binned2 = (unsigned int*)(ws + B2_OFF);

    // zero histS + histF (and harmlessly the space between)
    hipMemsetAsync(ws, 0, 24 * 1024, stream);

    hist_super_kernel<<<256, 256, 0, stream>>>(bidx + E, histS, E, nsuper);
    scan_super_kernel<<<1, 64, 0, stream>>>(histS, super_start, super_cursor, nsuper);

    int g1 = (E + CHUNK1 - 1) / CHUNK1;
    pass1_kernel<<<g1, 256, 0, stream>>>(bidx, super_cursor, binned1, histF,
                                         E, nsuper, nfine);

    scan_fine_kernel<<<1, 256, 0, stream>>>(histF, fine_start, fine_cursor, nfine);

    int g2 = (E + CHUNK2 - 1) / CHUNK2;
    pass2_kernel<<<g2, 256, 0, stream>>>(binned1, fine_cursor, binned2, E, nfine);

    gather_bin_kernel<<<nfine, 256, 0, stream>>>(
        (const float4*)x, fine_start, binned2, (float4*)out, NOUT);
}